// Round 12
// baseline (1016.550 us; speedup 1.0000x reference)
//
#include <hip/hip_runtime.h>
#include <hip/hip_bf16.h>

typedef unsigned short u16;
typedef unsigned int   u32;
typedef __attribute__((ext_vector_type(8))) short short8;   // 8 bf16 (MFMA A/B frag)
typedef __attribute__((ext_vector_type(4))) float f32x4;    // MFMA C/D frag

#define T_TOK 4096
#define HDIM  2048
#define NEXP  16
#define IDIM  1024
#define SIDIM 4096
#define RCAP  6144
#define NTIL  48

// ---- workspace layout (bytes) ----
#define O_WT      0u
#define O_EIDX    16384u
#define O_CNT     32768u
#define O_POS     32832u
#define O_PADOFF  32896u
#define O_TILEEXP 33024u
#define O_TOKROW  33280u
#define O_XBF     65536u                               // bf16[T][H]
#define O_XSC     (O_XBF  + 2u*T_TOK*HDIM)             // bf16[RCAP][H]
#define O_ACTS    (O_XSC  + 2u*RCAP*HDIM)              // bf16[T][SI]
#define O_ACTR    (O_ACTS + 2u*T_TOK*SIDIM)            // bf16[RCAP][I]
#define O_WSGT    (O_ACTR + 2u*RCAP*IDIM)              // bf16[SI][H]
#define O_WSUT    (O_WSGT + 2u*SIDIM*HDIM)
#define O_WSDT    (O_WSUT + 2u*SIDIM*HDIM)             // bf16[H][SI]

__device__ __forceinline__ u16 f2b(float f) {  // fp32 -> bf16, RNE
  u32 u = __float_as_uint(f);
  u = (u + 0x7FFFu + ((u >> 16) & 1u)) >> 16;
  return (u16)u;
}

__device__ __forceinline__ u32 cvtpk(float a, float b) {  // {lo:bf16(a), hi:bf16(b)}
  u32 r;
  asm("v_cvt_pk_bf16_f32 %0, %1, %2" : "=v"(r) : "v"(a), "v"(b));
  return r;
}

#define GLDS16(g, l) __builtin_amdgcn_global_load_lds( \
    (const __attribute__((address_space(1))) void*)(g), \
    (__attribute__((address_space(3))) void*)(l), 16, 0, 0)
#define BARX() __builtin_amdgcn_s_barrier()
#define SETPRIO(x) __builtin_amdgcn_s_setprio(x)
#define WAITVM(n) asm volatile("s_waitcnt vmcnt(" #n ")" ::: "memory")

// ---------------- router: fp64 logits, top-1, sigmoid; also emits xbf ----------------
__global__ __launch_bounds__(256) void router_k(
    const float* __restrict__ x, const float* __restrict__ rw,
    float* __restrict__ wt, int* __restrict__ eidx, int* __restrict__ cnt,
    u16* __restrict__ xbf) {
  int w = threadIdx.x >> 6, l = threadIdx.x & 63;
  int t = blockIdx.x * 4 + w;
  double acc[NEXP];
#pragma unroll
  for (int e = 0; e < NEXP; ++e) acc[e] = 0.0;
  const float* xp = x + (size_t)t * HDIM;
  u16* xo = xbf + (size_t)t * HDIM;
  for (int hb = 0; hb < HDIM; hb += 256) {
    float4 xv = *(const float4*)(xp + hb + l * 4);
    uint2 o;
    o.x = (u32)f2b(xv.x) | ((u32)f2b(xv.y) << 16);
    o.y = (u32)f2b(xv.z) | ((u32)f2b(xv.w) << 16);
    *(uint2*)(xo + hb + l * 4) = o;
#pragma unroll
    for (int e = 0; e < NEXP; ++e) {
      float4 wv = *(const float4*)(rw + (size_t)e * HDIM + hb + l * 4);
      acc[e] += (double)xv.x * wv.x + (double)xv.y * wv.y
              + (double)xv.z * wv.z + (double)xv.w * wv.w;
    }
  }
#pragma unroll
  for (int e = 0; e < NEXP; ++e) {
    double v = acc[e];
#pragma unroll
    for (int off = 32; off; off >>= 1) v += __shfl_xor(v, off, 64);
    acc[e] = v;
  }
  if (l == 0) {
    double best = acc[0]; int be = 0;
#pragma unroll
    for (int e = 1; e < NEXP; ++e) if (acc[e] > best) { best = acc[e]; be = e; }
    wt[t] = 1.0f / (1.0f + __expf(-(float)best));
    eidx[t] = be;
    atomicAdd(&cnt[be], 1);
  }
}

__global__ void scan_k(const int* __restrict__ cnt, int* __restrict__ pad_off,
                       int* __restrict__ tile_exp, int* __restrict__ pos,
                       int* __restrict__ tok_row) {
  if (threadIdx.x == 0) {
    for (int i = 0; i < 64; ++i) tile_exp[i] = -1;
    int run = 0;
    for (int e = 0; e < NEXP; ++e) {
      pad_off[e] = run;
      int pc = ((cnt[e] + 127) >> 7) << 7;
      for (int tt = run >> 7; tt < (run + pc) >> 7; ++tt) tile_exp[tt] = e;
      run += pc;
      pos[e] = 0;
    }
    pad_off[NEXP] = run;
  }
  for (int i = threadIdx.x; i < RCAP; i += 256) tok_row[i] = -1;
}

__global__ void assign_k(const int* __restrict__ eidx, const int* __restrict__ pad_off,
                         int* __restrict__ pos, int* __restrict__ tok_row) {
  int t = blockIdx.x * 256 + threadIdx.x;
  if (t >= T_TOK) return;
  int e = eidx[t];
  int r = atomicAdd(&pos[e], 1);
  tok_row[pad_off[e] + r] = t;
}

// ---------------- gathered + router-weighted x -> xsc (bf16) ----------------
__global__ __launch_bounds__(256) void gather_k(
    const float* __restrict__ x, const float* __restrict__ wt,
    const int* __restrict__ tok_row, u16* __restrict__ xsc) {
  int g = blockIdx.x;
  int tid = threadIdx.x;
  u16* dst = xsc + (size_t)g * HDIM;
  int t = tok_row[g];
  if (t < 0) {
    uint2 z; z.x = 0u; z.y = 0u;
#pragma unroll
    for (int i = 0; i < 2; ++i) *(uint2*)(dst + i * 1024 + tid * 4) = z;
  } else {
    float s = wt[t];
    const float* src = x + (size_t)t * HDIM;
#pragma unroll
    for (int i = 0; i < 2; ++i) {
      int c = i * 1024 + tid * 4;
      float4 v = *(const float4*)(src + c);
      uint2 o;
      o.x = (u32)f2b(v.x * s) | ((u32)f2b(v.y * s) << 16);
      o.y = (u32)f2b(v.z * s) | ((u32)f2b(v.w * s) << 16);
      *(uint2*)(dst + c) = o;
    }
  }
}

// ---------------- shared-weight transpose-convert: fp32 [K][N] -> bf16 [N][K] ----------------
__device__ __forceinline__ void conv_tile(
    const float* __restrict__ src, u16* __restrict__ dst, int K, int N,
    int bx, int ky, u32 (*lt)[36], int tid) {
  const int n0 = bx * 64, k0 = ky * 64;
  const int l = tid & 63, w = tid >> 6;
  const float* sp = src + (size_t)(k0 + w * 16) * N + n0 + l;
  u32 p[8];
#pragma unroll
  for (int i = 0; i < 8; ++i) {
    float a = sp[(size_t)(2 * i) * N];
    float b = sp[(size_t)(2 * i + 1) * N];
    p[i] = (u32)f2b(a) | ((u32)f2b(b) << 16);
  }
  *(uint4*)&lt[l][w * 8 + 0] = make_uint4(p[0], p[1], p[2], p[3]);
  *(uint4*)&lt[l][w * 8 + 4] = make_uint4(p[4], p[5], p[6], p[7]);
  __syncthreads();
  const int c = tid & 7, n2 = tid >> 3;
#pragma unroll
  for (int rnd = 0; rnd < 2; ++rnd) {
    int n = n2 + rnd * 32;
    uint4 v = *(const uint4*)&lt[n][c * 4];
    *(uint4*)(dst + (size_t)(n0 + n) * K + k0 + c * 8) = v;
  }
}

__global__ __launch_bounds__(256) void megaconv(
    const float* __restrict__ wsg, const float* __restrict__ wsu,
    const float* __restrict__ wsd, u16* wsgT, u16* wsuT, u16* wsdT) {
  __shared__ u32 lt[64][36];
  int idx = blockIdx.x, tid = threadIdx.x;
  if (idx < 2048) {
    conv_tile(wsg, wsgT, 2048, 4096, idx & 63, idx >> 6, lt, tid);
  } else if (idx < 4096) { idx -= 2048;
    conv_tile(wsu, wsuT, 2048, 4096, idx & 63, idx >> 6, lt, tid);
  } else { idx -= 4096;
    conv_tile(wsd, wsdT, 4096, 2048, idx & 31, idx >> 5, lt, tid);
  }
}

// ================= merged-phase 256-row shared GEMMs (round-7, passing) =================

// ---- shared gate/up
__global__ __launch_bounds__(512, 2) void gu_sh8(
    const u16* __restrict__ A, const u16* __restrict__ Bg, const u16* __restrict__ Bu,
    u16* __restrict__ act) {
  extern __shared__ u16 sm[];
  u16* As  = sm;            // [2][2][8192]
  u16* Bsm = sm + 32768;    // [2][2][8192]
  const int bid = blockIdx.x;
  const int xcd = bid & 7, bi = bid >> 3;
  const int bx = xcd * 4 + (bi & 3), by = bi >> 2;
  const int m0 = by * 256, c0 = bx * 128;
  const int tid = threadIdx.x, l = tid & 63, wid = tid >> 6;
  const int wm = wid >> 1, wn = wid & 1;

  const int cpos = tid & 3, rr = tid >> 2;
  const int gc = (cpos ^ ((rr >> 1) & 3)) * 8;
  const u16* aS0 = A + (size_t)(m0 + rr) * HDIM + gc;
  const u16* aS1 = A + (size_t)(m0 + 128 + rr) * HDIM + gc;
  const int mat = (rr >> 6) & 1;
  const u16* bbase = mat ? Bu : Bg;
  const u16* bS0 = bbase + (size_t)(c0 + (rr & 63)) * HDIM + gc;
  const u16* bS1 = bbase + (size_t)(c0 + 64 + (rr & 63)) * HDIM + gc;
  const int ld0 = tid * 8, ld1 = (512 + tid) * 8;

#define STA_G(bb, kh, koff) do { \
    GLDS16(aS0 + (koff) + (kh) * 32, As + ((bb) * 2 + (kh)) * 8192 + ld0); \
    GLDS16(aS1 + (koff) + (kh) * 32, As + ((bb) * 2 + (kh)) * 8192 + ld1); } while (0)
#define STB_G(bb, kh, koff) do { \
    GLDS16(bS0 + (koff) + (kh) * 32, Bsm + ((bb) * 2 + (kh)) * 8192 + ld0); \
    GLDS16(bS1 + (koff) + (kh) * 32, Bsm + ((bb) * 2 + (kh)) * 8192 + ld1); } while (0)

  const int fch = ((l >> 4) ^ ((l >> 1) & 3)) * 8;
  int aoff[4], boff[8];
#pragma unroll
  for (int mf = 0; mf < 4; ++mf) aoff[mf] = (wm * 64 + mf * 16 + (l & 15)) * 32 + fch;
#pragma unroll
  for (int i = 0; i < 8; ++i) {
    int v = wn * 128 + (i >> 2) * 64 + (i & 3) * 16 + (l & 15);
    boff[i] = v * 32 + fch;
  }
#define LDA_G(bb, kh) do { const u16* s_ = As + ((bb) * 2 + (kh)) * 8192; \
    af[0] = *(const short8*)(s_ + aoff[0]); af[1] = *(const short8*)(s_ + aoff[1]); \
    af[2] = *(const short8*)(s_ + aoff[2]); af[3] = *(const short8*)(s_ + aoff[3]); } while (0)
#define LDB_G(bb, kh, h, d) do { const u16* s_ = Bsm + ((bb) * 2 + (kh)) * 8192; \
    d[0] = *(const short8*)(s_ + boff[(h) * 4 + 0]); d[1] = *(const short8*)(s_ + boff[(h) * 4 + 1]); \
    d[2] = *(const short8*)(s_ + boff[(h) * 4 + 2]); d[3] = *(const short8*)(s_ + boff[(h) * 4 + 3]); } while (0)
#define MM32_G() do { SETPRIO(1); \
    _Pragma("unroll") for (int mf = 0; mf < 4; ++mf) { \
      _Pragma("unroll") for (int nf = 0; nf < 4; ++nf) \
        acc[mf][nf] = __builtin_amdgcn_mfma_f32_16x16x32_bf16(af[mf], bfrA[nf], acc[mf][nf], 0, 0, 0); \
      _Pragma("unroll") for (int nf = 0; nf < 4; ++nf) \
        acc[mf][4 + nf] = __builtin_amdgcn_mfma_f32_16x16x32_bf16(af[mf], bfrB[nf], acc[mf][4 + nf], 0, 0, 0); \
    } SETPRIO(0); } while (0)

  f32x4 acc[4][8];
#pragma unroll
  for (int i = 0; i < 4; ++i)
#pragma unroll
    for (int j = 0; j < 8; ++j)
#pragma unroll
      for (int r = 0; r < 4; ++r) acc[i][j][r] = 0.0f;
  short8 af[4], bfrA[4], bfrB[4];

  STA_G(0, 0, 0); STB_G(0, 0, 0); STA_G(0, 1, 0); STB_G(0, 1, 0);
  WAITVM(4); BARX();
  const int NT = HDIM / 64;
  for (int t = 0; t < NT - 1; ++t) {
    const int b = t & 1, nb = b ^ 1, kn = (t + 1) * 64;
    LDA_G(b, 0); LDB_G(b, 0, 0, bfrA); LDB_G(b, 0, 1, bfrB);
    STA_G(nb, 0, kn); STB_G(nb, 0, kn);
    MM32_G(); WAITVM(4); BARX();
    LDA_G(b, 1); LDB_G(b, 1, 0, bfrA); LDB_G(b, 1, 1, bfrB);
    STA_G(nb, 1, kn); STB_G(nb, 1, kn);
    MM32_G(); WAITVM(4); BARX();
  }
  { const int b = (NT - 1) & 1;
    LDA_G(b, 0); LDB_G(b, 0, 0, bfrA); LDB_G(b, 0, 1, bfrB);
    MM32_G(); WAITVM(0); BARX();
    LDA_G(b, 1); LDB_G(b, 1, 0, bfrA); LDB_G(b, 1, 1, bfrB);
    MM32_G();
  }
#pragma unroll
  for (int mf = 0; mf < 4; ++mf)
#pragma unroll
    for (int nf = 0; nf < 4; ++nf) {
      int col = c0 + wn * 64 + nf * 16 + (l & 15);
      int rowb = m0 + wm * 64 + mf * 16 + (l >> 4) * 4;
#pragma unroll
      for (int r = 0; r < 4; ++r) {
        float g = acc[mf][nf][r], u = acc[mf][4 + nf][r];
        float s = g / (1.0f + __expf(-g));
        act[(size_t)(rowb + r) * SIDIM + col] = f2b(s * u);
      }
    }
#undef STA_G
#undef STB_G
#undef LDA_G
#undef LDB_G
#undef MM32_G
}

// ---- shared down
__global__ __launch_bounds__(512, 2) void dn_sh8(
    const u16* __restrict__ A, const u16* __restrict__ B, float* __restrict__ out) {
  extern __shared__ u16 sm[];
  u16* As  = sm;            // [2][2][8192]
  u16* Bsm = sm + 32768;    // [2][2][4096]
  const int bid = blockIdx.x;
  const int xcd = bid & 7, bi = bid >> 3;
  const int bx = xcd * 2 + (bi & 1), by = bi >> 1;
  const int m0 = by * 256, c0 = bx * 128;
  const int tid = threadIdx.x, l = tid & 63, wid = tid >> 6;
  const int wm = wid >> 1, wn = wid & 1;

  const int cpos = tid & 3, rr = tid >> 2;
  const int gc = (cpos ^ ((rr >> 1) & 3)) * 8;
  const u16* aS0 = A + (size_t)(m0 + rr) * SIDIM + gc;
  const u16* aS1 = A + (size_t)(m0 + 128 + rr) * SIDIM + gc;
  const u16* bS  = B + (size_t)(c0 + rr) * SIDIM + gc;
  const int ld0 = tid * 8, ld1 = (512 + tid) * 8;

#define STA_D(bb, kh, koff) do { \
    GLDS16(aS0 + (koff) + (kh) * 32, As + ((bb) * 2 + (kh)) * 8192 + ld0); \
    GLDS16(aS1 + (koff) + (kh) * 32, As + ((bb) * 2 + (kh)) * 8192 + ld1); } while (0)
#define STB_D(bb, kh, koff) \
    GLDS16(bS + (koff) + (kh) * 32, Bsm + ((bb) * 2 + (kh)) * 4096 + ld0)

  const int fch = ((l >> 4) ^ ((l >> 1) & 3)) * 8;
  int aoff[4], boff[4];
#pragma unroll
  for (int mf = 0; mf < 4; ++mf) aoff[mf] = (wm * 64 + mf * 16 + (l & 15)) * 32 + fch;
#pragma unroll
  for (int i = 0; i < 4; ++i) {
    int v = wn * 64 + (i >> 1) * 32 + (i & 1) * 16 + (l & 15);
    boff[i] = v * 32 + fch;
  }
#define LDA_D(bb, kh) do { const u16* s_ = As + ((bb) * 2 + (kh)) * 8192; \
    af[0] = *(const short8*)(s_ + aoff[0]); af[1] = *(const short8*)(s_ + aoff[1]); \
    af[2] = *(const short8*)(s_ + aoff[2]); af[3] = *(const short8*)(s_ + aoff[3]); } while (0)
#define LDB_D(bb, kh, h, d) do { const u16* s_ = Bsm + ((bb) * 2 + (kh)) * 4096; \
    d[0] = *(const short8*)(s_ + boff[(h) * 2 + 0]); \
    d[1] = *(const short8*)(s_ + boff[(h) * 2 + 1]); } while (0)
#define MM16_D() do { SETPRIO(1); \
    _Pragma("unroll") for (int mf = 0; mf < 4; ++mf) { \
      acc[mf][0] = __builtin_amdgcn_mfma_f32_16x16x32_bf16(af[mf], bfrA[0], acc[mf][0], 0, 0, 0); \
      acc[mf][1] = __builtin_amdgcn_mfma_f32_16x16x32_bf16(af[mf], bfrA[1], acc[mf][1], 0, 0, 0); \
      acc[mf][2] = __builtin_amdgcn_mfma_f32_16x16x32_bf16(af[mf], bfrB[0], acc[mf][2], 0, 0, 0); \
      acc[mf][3] = __builtin_amdgcn_mfma_f32_16x16x32_bf16(af[mf], bfrB[1], acc[mf][3], 0, 0, 0); \
    } SETPRIO(0); } while (0)

  f32x4 acc[4][4];
#pragma unroll
  for (int i = 0; i < 4; ++i)
#pragma unroll
    for (int j = 0; j < 4; ++j)
#pragma unroll
      for (int r = 0; r < 4; ++r) acc[i][j][r] = 0.0f;
  short8 af[4], bfrA[2], bfrB[2];

  STA_D(0, 0, 0); STB_D(0, 0, 0); STA_D(0, 1, 0); STB_D(0, 1, 0);
  WAITVM(3); BARX();
  const int NT = SIDIM / 64;
  for (int t = 0; t < NT - 1; ++t) {
    const int b = t & 1, nb = b ^ 1, kn = (t + 1) * 64;
    LDA_D(b, 0); LDB_D(b, 0, 0, bfrA); LDB_D(b, 0, 1, bfrB);
    STA_D(nb, 0, kn); STB_D(nb, 0, kn);
    MM16_D(); WAITVM(3); BARX();
    LDA_D(b, 1); LDB_D(b, 1, 0, bfrA); LDB_D(b, 1, 1, bfrB);
    STA_D(nb, 1, kn); STB_D(nb, 1, kn);
    MM16_D(); WAITVM(3); BARX();
  }
  { const int b = (NT - 1) & 1;
    LDA_D(b, 0); LDB_D(b, 0, 0, bfrA); LDB_D(b, 0, 1, bfrB);
    MM16_D(); WAITVM(0); BARX();
    LDA_D(b, 1); LDB_D(b, 1, 0, bfrA); LDB_D(b, 1, 1, bfrB);
    MM16_D();
  }
#pragma unroll
  for (int mf = 0; mf < 4; ++mf)
#pragma unroll
    for (int nf = 0; nf < 4; ++nf) {
      int col = c0 + wn * 64 + (nf >> 1) * 32 + (nf & 1) * 16 + (l & 15);
      int rowb = m0 + wm * 64 + mf * 16 + (l >> 4) * 4;
#pragma unroll
      for (int r = 0; r < 4; ++r)
        out[(size_t)(rowb + r) * HDIM + col] = acc[mf][nf][r];
    }
#undef STA_D
#undef STB_D
#undef LDA_D
#undef LDB_D
#undef MM16_D
}

// ================= routed GEMMs: LDS-FREE, barrier-free, direct fragment loads =================
// Streaming weights have zero reuse -> no LDS, no barriers; latency hidden by TLP.
// A frag (verified layout): 16B contiguous at A[row = m0+wm*64+mf*16+(l&15)][k0+q*8], q=kh*4+(l>>4).
// B frag: 8 k-strided fp32 at col n0+...+(l&15) -> v_cvt_pk_bf16_f32 pairs.

__global__ __launch_bounds__(256) void gu_rf(
    const u16* __restrict__ A, const float* __restrict__ Bg0, const float* __restrict__ Bu0,
    u16* __restrict__ act, const int* __restrict__ tile_exp) {
  const int tid = threadIdx.x;
  const int l = tid & 63, w = tid >> 6;
  const int wm = w >> 1, wn = w & 1;
  const int m0 = blockIdx.y * 128, n0 = blockIdx.x * 32;
  int e = tile_exp[blockIdx.y];
  if (e < 0) return;
  size_t eo = (size_t)e * HDIM * IDIM;
  const int col = wn * 16 + (l & 15);
  const int q0 = l >> 4;
  const float* Bg = Bg0 + eo + n0 + col;
  const float* Bu = Bu0 + eo + n0 + col;
  const u16* Ar = A + (size_t)(m0 + wm * 64 + (l & 15)) * HDIM;

  f32x4 accg[4], accu[4];
#pragma unroll
  for (int i = 0; i < 4; ++i)
#pragma unroll
    for (int r = 0; r < 4; ++r) { accg[i][r] = 0.0f; accu[i][r] = 0.0f; }

  for (int k0 = 0; k0 < HDIM; k0 += 64) {
    short8 af[2][4];
    float bg[2][8], bu[2][8];
#pragma unroll
    for (int kh = 0; kh < 2; ++kh) {
      const int kq = k0 + (kh * 4 + q0) * 8;
#pragma unroll
      for (int mf = 0; mf < 4; ++mf)
        af[kh][mf] = *(const short8*)(Ar + (size_t)(mf * 16) * HDIM + kq);
#pragma unroll
      for (int j = 0; j < 8; ++j) {
        bg[kh][j] = Bg[(size_t)(kq + j) * IDIM];
        bu[kh][j] = Bu[(size_t)(kq + j) * IDIM];
      }
    }
#pragma unroll
    for (int kh = 0; kh < 2; ++kh) {
      int4 pg, pu;
      pg.x = cvtpk(bg[kh][0], bg[kh][1]); pg.y = cvtpk(bg[kh][2], bg[kh][3]);
      pg.z = cvtpk(bg[kh][4], bg[kh][5]); pg.w = cvtpk(bg[kh][6], bg[kh][7]);
      pu.x = cvtpk(bu[kh][0], bu[kh][1]); pu.y = cvtpk(bu[kh][2], bu[kh][3]);
      pu.z = cvtpk(bu[kh][4], bu[kh][5]); pu.w = cvtpk(bu[kh][6], bu[kh][7]);
      short8 bgf = *(short8*)&pg, buf2 = *(short8*)&pu;
#pragma unroll
      for (int mf = 0; mf < 4; ++mf) {
        accg[mf] = __builtin_amdgcn_mfma_f32_16x16x32_bf16(af[kh][mf], bgf,  accg[mf], 0, 0, 0);
        accu[mf] = __builtin_amdgcn_mfma_f32_16x16x32_bf16(af[kh][mf], buf2, accu[mf], 0, 0, 0);
      }
    }
  }
#pragma unroll
  for (int mf = 0; mf < 4; ++mf) {
    int ocol = n0 + wn * 16 + (l & 15);
#pragma unroll
    for (int r = 0; r < 4; ++r) {
      int row = m0 + wm * 64 + mf * 16 + (l >> 4) * 4 + r;
      float g = accg[mf][r], u = accu[mf][r];
      float s = g / (1.0f + __expf(-g));
      act[(size_t)row * IDIM + ocol] = f2b(s * u);
    }
  }
}

__global__ __launch_bounds__(256) void dn_rf(
    const u16* __restrict__ A, const float* __restrict__ B0, float* __restrict__ out,
    const int* __restrict__ tile_exp, const int* __restrict__ tok_row) {
  const int tid = threadIdx.x;
  const int l = tid & 63, w = tid >> 6;
  const int wm = w >> 1, wn = w & 1;
  const int m0 = blockIdx.y * 128, n0 = blockIdx.x * 64;
  int e = tile_exp[blockIdx.y];
  if (e < 0) return;
  const float* B = B0 + (size_t)e * IDIM * HDIM + n0;
  const int q0 = l >> 4;
  const u16* Ar = A + (size_t)(m0 + wm * 64 + (l & 15)) * IDIM;
  int bcol[2];
#pragma unroll
  for (int nf = 0; nf < 2; ++nf) bcol[nf] = wn * 32 + nf * 16 + (l & 15);

  f32x4 acc[4][2];
#pragma unroll
  for (int i = 0; i < 4; ++i)
#pragma unroll
    for (int j = 0; j < 2; ++j)
#pragma unroll
      for (int r = 0; r < 4; ++r) acc[i][j][r] = 0.0f;

  for (int k0 = 0; k0 < IDIM; k0 += 64) {
    short8 af[2][4];
    float bb[2][2][8];
#pragma unroll
    for (int kh = 0; kh < 2; ++kh) {
      const int kq = k0 + (kh * 4 + q0) * 8;
#pragma unroll
      for (int mf = 0; mf < 4; ++mf)
        af[kh][mf] = *(const short8*)(Ar + (size_t)(mf * 16) * IDIM + kq);
#pragma unroll
      for (int nf = 0; nf < 2; ++nf)
#pragma unroll
        for (int j = 0; j < 8; ++j)
          bb[kh][nf][j] = B[(size_t)(kq + j) * HDIM + bcol[nf]];
    }
#pragma unroll
    for (int kh = 0; kh < 2; ++kh) {
      short8 bf[2];
#pragma unroll
      for (int nf = 0; nf < 2; ++nf) {
        int4 p;
        p.x = cvtpk(bb[kh][nf][0], bb[kh][nf][1]); p.y = cvtpk(bb[kh][nf][2], bb[kh][nf][3]);
        p.z = cvtpk(bb[kh][nf][4], bb[kh][nf][5]); p.w = cvtpk(bb[kh][nf][6], bb[kh][nf][7]);
        bf[nf] = *(short8*)&p;
      }
#pragma unroll
      for (int mf = 0; mf < 4; ++mf)
#pragma unroll
        for (int nf = 0; nf < 2; ++nf)
          acc[mf][nf] = __builtin_amdgcn_mfma_f32_16x16x32_bf16(af[kh][mf], bf[nf], acc[mf][nf], 0, 0, 0);
    }
  }
#pragma unroll
  for (int mf = 0; mf < 4; ++mf)
#pragma unroll
    for (int nf = 0; nf < 2; ++nf) {
      int col = n0 + wn * 32 + nf * 16 + (l & 15);
#pragma unroll
      for (int r = 0; r < 4; ++r) {
        int grow = m0 + wm * 64 + mf * 16 + (l >> 4) * 4 + r;
        int t = tok_row[grow];
        if (t >= 0) out[(size_t)t * HDIM + col] += acc[mf][nf][r];
      }
    }
}

extern "C" void kernel_launch(void* const* d_in, const int* in_sizes, int n_in,
                              void* d_out, int out_size, void* d_ws, size_t ws_size,
                              hipStream_t stream) {
  const float* x   = (const float*)d_in[0];
  const float* rw  = (const float*)d_in[1];
  const float* wg  = (const float*)d_in[2];
  const float* wu  = (const float*)d_in[3];
  const float* wd  = (const float*)d_in[4];
  const float* wsg = (const float*)d_in[5];
  const float* wsu = (const float*)d_in[6];
  const float* wsd = (const float*)d_in[7];
  float* out = (float*)d_out;
  char* ws = (char*)d_ws;

  float* wt     = (float*)(ws + O_WT);
  int* eidx     = (int*)(ws + O_EIDX);
  int* cnt      = (int*)(ws + O_CNT);
  int* pos      = (int*)(ws + O_POS);
  int* pad_off  = (int*)(ws + O_PADOFF);
  int* tile_exp = (int*)(ws + O_TILEEXP);
  int* tok_row  = (int*)(ws + O_TOKROW);
  u16* xbf      = (u16*)(ws + O_XBF);
  u16* xsc      = (u16*)(ws + O_XSC);
  u16* acts     = (u16*)(ws + O_ACTS);
  u16* actr     = (u16*)(ws + O_ACTR);
  u16* wsgT     = (u16*)(ws + O_WSGT);
  u16* wsuT     = (u16*)(ws + O_WSUT);
  u16* wsdT     = (u16*)(ws + O_WSDT);

  hipFuncSetAttribute((const void*)gu_sh8, hipFuncAttributeMaxDynamicSharedMemorySize, 131072);
  hipFuncSetAttribute((const void*)dn_sh8, hipFuncAttributeMaxDynamicSharedMemorySize, 98304);

  hipMemsetAsync(ws + O_CNT, 0, 128, stream);
  megaconv<<<6144, 256, 0, stream>>>(wsg, wsu, wsd, wsgT, wsuT, wsdT);
  router_k<<<T_TOK / 4, 256, 0, stream>>>(x, rw, wt, eidx, cnt, xbf);
  scan_k<<<1, 256, 0, stream>>>(cnt, pad_off, tile_exp, pos, tok_row);
  assign_k<<<T_TOK / 256, 256, 0, stream>>>(eidx, pad_off, pos, tok_row);
  gather_k<<<RCAP, 256, 0, stream>>>(x, wt, tok_row, xsc);

  gu_sh8<<<512, 512, 131072, stream>>>(xbf, wsgT, wsuT, acts);
  gu_rf<<<dim3(IDIM / 32, NTIL), 256, 0, stream>>>(xsc, wg, wu, actr, tile_exp);
  dn_sh8<<<256, 512, 98304, stream>>>(acts, wsdT, out);
  dn_rf<<<dim3(HDIM / 64, NTIL), 256, 0, stream>>>(actr, wd, out, tile_exp, tok_row);
}

// Round 13
// 565.710 us; speedup vs baseline: 1.7969x; 1.7969x over previous
//
#include <hip/hip_runtime.h>
#include <hip/hip_bf16.h>

typedef unsigned short u16;
typedef unsigned int   u32;
typedef __attribute__((ext_vector_type(8))) short short8;   // 8 bf16 (MFMA A/B frag)
typedef __attribute__((ext_vector_type(4))) float f32x4;    // MFMA C/D frag

#define T_TOK 4096
#define HDIM  2048
#define NEXP  16
#define IDIM  1024
#define SIDIM 4096
#define RCAP  6144
#define NTIL  48

// ---- workspace layout (bytes) ----
#define O_WT      0u
#define O_EIDX    16384u
#define O_CNT     32768u
#define O_POS     32832u
#define O_PADOFF  32896u
#define O_TILEEXP 33024u
#define O_TOKROW  33280u
#define O_XBF     65536u                               // bf16[T][H]
#define O_XSC     (O_XBF  + 2u*T_TOK*HDIM)             // bf16[RCAP][H]
#define O_ACTS    (O_XSC  + 2u*RCAP*HDIM)              // bf16[T][SI]
#define O_ACTR    (O_ACTS + 2u*T_TOK*SIDIM)            // bf16[RCAP][I]
#define O_WSGT    (O_ACTR + 2u*RCAP*IDIM)              // bf16[SI][H]
#define O_WSUT    (O_WSGT + 2u*SIDIM*HDIM)
#define O_WSDT    (O_WSUT + 2u*SIDIM*HDIM)             // bf16[H][SI]

__device__ __forceinline__ u16 f2b(float f) {  // fp32 -> bf16, RNE
  u32 u = __float_as_uint(f);
  u = (u + 0x7FFFu + ((u >> 16) & 1u)) >> 16;
  return (u16)u;
}

#define GLDS16(g, l) __builtin_amdgcn_global_load_lds( \
    (const __attribute__((address_space(1))) void*)(g), \
    (__attribute__((address_space(3))) void*)(l), 16, 0, 0)
#define BARX() __builtin_amdgcn_s_barrier()
#define SETPRIO(x) __builtin_amdgcn_s_setprio(x)
#define WAITVM(n) asm volatile("s_waitcnt vmcnt(" #n ")" ::: "memory")

// ---------------- fused: shared-weight transpose-convert + router ----------------
// Blocks [0, 6144): conv tiles (HBM-bound). Blocks [6144, 7168): router (VALU-bound).
// Independent work items; co-scheduling overlaps the two pipes.

__device__ __forceinline__ void conv_tile(
    const float* __restrict__ src, u16* __restrict__ dst, int K, int N,
    int bx, int ky, u32 (*lt)[36], int tid) {
  const int n0 = bx * 64, k0 = ky * 64;
  const int l = tid & 63, w = tid >> 6;
  const float* sp = src + (size_t)(k0 + w * 16) * N + n0 + l;
  u32 p[8];
#pragma unroll
  for (int i = 0; i < 8; ++i) {
    float a = sp[(size_t)(2 * i) * N];
    float b = sp[(size_t)(2 * i + 1) * N];
    p[i] = (u32)f2b(a) | ((u32)f2b(b) << 16);
  }
  *(uint4*)&lt[l][w * 8 + 0] = make_uint4(p[0], p[1], p[2], p[3]);
  *(uint4*)&lt[l][w * 8 + 4] = make_uint4(p[4], p[5], p[6], p[7]);
  __syncthreads();
  const int c = tid & 7, n2 = tid >> 3;
#pragma unroll
  for (int rnd = 0; rnd < 2; ++rnd) {
    int n = n2 + rnd * 32;
    uint4 v = *(const uint4*)&lt[n][c * 4];
    *(uint4*)(dst + (size_t)(n0 + n) * K + k0 + c * 8) = v;
  }
}

__global__ __launch_bounds__(256) void megart(
    const float* __restrict__ wsg, const float* __restrict__ wsu,
    const float* __restrict__ wsd, u16* wsgT, u16* wsuT, u16* wsdT,
    const float* __restrict__ x, const float* __restrict__ rw,
    float* __restrict__ wt, int* __restrict__ eidx, int* __restrict__ cnt,
    u16* __restrict__ xbf) {
  __shared__ u32 lt[64][36];
  int idx = blockIdx.x, tid = threadIdx.x;
  if (idx < 2048) {
    conv_tile(wsg, wsgT, 2048, 4096, idx & 63, idx >> 6, lt, tid);
    return;
  } else if (idx < 4096) { idx -= 2048;
    conv_tile(wsu, wsuT, 2048, 4096, idx & 63, idx >> 6, lt, tid);
    return;
  } else if (idx < 6144) { idx -= 4096;
    conv_tile(wsd, wsdT, 4096, 2048, idx & 31, idx >> 5, lt, tid);
    return;
  }
  // ---- router branch ----
  idx -= 6144;
  int w = tid >> 6, l = tid & 63;
  int t = idx * 4 + w;
  double acc[NEXP];
#pragma unroll
  for (int e = 0; e < NEXP; ++e) acc[e] = 0.0;
  const float* xp = x + (size_t)t * HDIM;
  u16* xo = xbf + (size_t)t * HDIM;
  for (int hb = 0; hb < HDIM; hb += 256) {
    float4 xv = *(const float4*)(xp + hb + l * 4);
    uint2 o;
    o.x = (u32)f2b(xv.x) | ((u32)f2b(xv.y) << 16);
    o.y = (u32)f2b(xv.z) | ((u32)f2b(xv.w) << 16);
    *(uint2*)(xo + hb + l * 4) = o;
#pragma unroll
    for (int e = 0; e < NEXP; ++e) {
      float4 wv = *(const float4*)(rw + (size_t)e * HDIM + hb + l * 4);
      acc[e] += (double)xv.x * wv.x + (double)xv.y * wv.y
              + (double)xv.z * wv.z + (double)xv.w * wv.w;
    }
  }
#pragma unroll
  for (int e = 0; e < NEXP; ++e) {
    double v = acc[e];
#pragma unroll
    for (int off = 32; off; off >>= 1) v += __shfl_xor(v, off, 64);
    acc[e] = v;
  }
  if (l == 0) {
    double best = acc[0]; int be = 0;
#pragma unroll
    for (int e = 1; e < NEXP; ++e) if (acc[e] > best) { best = acc[e]; be = e; }
    wt[t] = 1.0f / (1.0f + __expf(-(float)best));
    eidx[t] = be;
    atomicAdd(&cnt[be], 1);
  }
}

__global__ void scan_k(const int* __restrict__ cnt, int* __restrict__ pad_off,
                       int* __restrict__ tile_exp, int* __restrict__ pos,
                       int* __restrict__ tok_row) {
  if (threadIdx.x == 0) {
    for (int i = 0; i < 64; ++i) tile_exp[i] = -1;
    int run = 0;
    for (int e = 0; e < NEXP; ++e) {
      pad_off[e] = run;
      int pc = ((cnt[e] + 127) >> 7) << 7;
      for (int tt = run >> 7; tt < (run + pc) >> 7; ++tt) tile_exp[tt] = e;
      run += pc;
      pos[e] = 0;
    }
    pad_off[NEXP] = run;
  }
  for (int i = threadIdx.x; i < RCAP; i += 256) tok_row[i] = -1;
}

__global__ void assign_k(const int* __restrict__ eidx, const int* __restrict__ pad_off,
                         int* __restrict__ pos, int* __restrict__ tok_row) {
  int t = blockIdx.x * 256 + threadIdx.x;
  if (t >= T_TOK) return;
  int e = eidx[t];
  int r = atomicAdd(&pos[e], 1);
  tok_row[pad_off[e] + r] = t;
}

// ---------------- gathered + router-weighted x -> xsc (bf16) ----------------
__global__ __launch_bounds__(256) void gather_k(
    const float* __restrict__ x, const float* __restrict__ wt,
    const int* __restrict__ tok_row, u16* __restrict__ xsc) {
  int g = blockIdx.x;
  int tid = threadIdx.x;
  u16* dst = xsc + (size_t)g * HDIM;
  int t = tok_row[g];
  if (t < 0) {
    uint2 z; z.x = 0u; z.y = 0u;
#pragma unroll
    for (int i = 0; i < 2; ++i) *(uint2*)(dst + i * 1024 + tid * 4) = z;
  } else {
    float s = wt[t];
    const float* src = x + (size_t)t * HDIM;
#pragma unroll
    for (int i = 0; i < 2; ++i) {
      int c = i * 1024 + tid * 4;
      float4 v = *(const float4*)(src + c);
      uint2 o;
      o.x = (u32)f2b(v.x * s) | ((u32)f2b(v.y * s) << 16);
      o.y = (u32)f2b(v.z * s) | ((u32)f2b(v.w * s) << 16);
      *(uint2*)(dst + c) = o;
    }
  }
}

// ================= merged-phase 256-row shared GEMMs (round-7, passing) =================

// ---- shared gate/up
__global__ __launch_bounds__(512, 2) void gu_sh8(
    const u16* __restrict__ A, const u16* __restrict__ Bg, const u16* __restrict__ Bu,
    u16* __restrict__ act) {
  extern __shared__ u16 sm[];
  u16* As  = sm;            // [2][2][8192]
  u16* Bsm = sm + 32768;    // [2][2][8192]
  const int bid = blockIdx.x;
  const int xcd = bid & 7, bi = bid >> 3;
  const int bx = xcd * 4 + (bi & 3), by = bi >> 2;
  const int m0 = by * 256, c0 = bx * 128;
  const int tid = threadIdx.x, l = tid & 63, wid = tid >> 6;
  const int wm = wid >> 1, wn = wid & 1;

  const int cpos = tid & 3, rr = tid >> 2;
  const int gc = (cpos ^ ((rr >> 1) & 3)) * 8;
  const u16* aS0 = A + (size_t)(m0 + rr) * HDIM + gc;
  const u16* aS1 = A + (size_t)(m0 + 128 + rr) * HDIM + gc;
  const int mat = (rr >> 6) & 1;
  const u16* bbase = mat ? Bu : Bg;
  const u16* bS0 = bbase + (size_t)(c0 + (rr & 63)) * HDIM + gc;
  const u16* bS1 = bbase + (size_t)(c0 + 64 + (rr & 63)) * HDIM + gc;
  const int ld0 = tid * 8, ld1 = (512 + tid) * 8;

#define STA_G(bb, kh, koff) do { \
    GLDS16(aS0 + (koff) + (kh) * 32, As + ((bb) * 2 + (kh)) * 8192 + ld0); \
    GLDS16(aS1 + (koff) + (kh) * 32, As + ((bb) * 2 + (kh)) * 8192 + ld1); } while (0)
#define STB_G(bb, kh, koff) do { \
    GLDS16(bS0 + (koff) + (kh) * 32, Bsm + ((bb) * 2 + (kh)) * 8192 + ld0); \
    GLDS16(bS1 + (koff) + (kh) * 32, Bsm + ((bb) * 2 + (kh)) * 8192 + ld1); } while (0)

  const int fch = ((l >> 4) ^ ((l >> 1) & 3)) * 8;
  int aoff[4], boff[8];
#pragma unroll
  for (int mf = 0; mf < 4; ++mf) aoff[mf] = (wm * 64 + mf * 16 + (l & 15)) * 32 + fch;
#pragma unroll
  for (int i = 0; i < 8; ++i) {
    int v = wn * 128 + (i >> 2) * 64 + (i & 3) * 16 + (l & 15);
    boff[i] = v * 32 + fch;
  }
#define LDA_G(bb, kh) do { const u16* s_ = As + ((bb) * 2 + (kh)) * 8192; \
    af[0] = *(const short8*)(s_ + aoff[0]); af[1] = *(const short8*)(s_ + aoff[1]); \
    af[2] = *(const short8*)(s_ + aoff[2]); af[3] = *(const short8*)(s_ + aoff[3]); } while (0)
#define LDB_G(bb, kh, h, d) do { const u16* s_ = Bsm + ((bb) * 2 + (kh)) * 8192; \
    d[0] = *(const short8*)(s_ + boff[(h) * 4 + 0]); d[1] = *(const short8*)(s_ + boff[(h) * 4 + 1]); \
    d[2] = *(const short8*)(s_ + boff[(h) * 4 + 2]); d[3] = *(const short8*)(s_ + boff[(h) * 4 + 3]); } while (0)
#define MM32_G() do { SETPRIO(1); \
    _Pragma("unroll") for (int mf = 0; mf < 4; ++mf) { \
      _Pragma("unroll") for (int nf = 0; nf < 4; ++nf) \
        acc[mf][nf] = __builtin_amdgcn_mfma_f32_16x16x32_bf16(af[mf], bfrA[nf], acc[mf][nf], 0, 0, 0); \
      _Pragma("unroll") for (int nf = 0; nf < 4; ++nf) \
        acc[mf][4 + nf] = __builtin_amdgcn_mfma_f32_16x16x32_bf16(af[mf], bfrB[nf], acc[mf][4 + nf], 0, 0, 0); \
    } SETPRIO(0); } while (0)

  f32x4 acc[4][8];
#pragma unroll
  for (int i = 0; i < 4; ++i)
#pragma unroll
    for (int j = 0; j < 8; ++j)
#pragma unroll
      for (int r = 0; r < 4; ++r) acc[i][j][r] = 0.0f;
  short8 af[4], bfrA[4], bfrB[4];

  STA_G(0, 0, 0); STB_G(0, 0, 0); STA_G(0, 1, 0); STB_G(0, 1, 0);
  WAITVM(4); BARX();
  const int NT = HDIM / 64;
  for (int t = 0; t < NT - 1; ++t) {
    const int b = t & 1, nb = b ^ 1, kn = (t + 1) * 64;
    LDA_G(b, 0); LDB_G(b, 0, 0, bfrA); LDB_G(b, 0, 1, bfrB);
    STA_G(nb, 0, kn); STB_G(nb, 0, kn);
    MM32_G(); WAITVM(4); BARX();
    LDA_G(b, 1); LDB_G(b, 1, 0, bfrA); LDB_G(b, 1, 1, bfrB);
    STA_G(nb, 1, kn); STB_G(nb, 1, kn);
    MM32_G(); WAITVM(4); BARX();
  }
  { const int b = (NT - 1) & 1;
    LDA_G(b, 0); LDB_G(b, 0, 0, bfrA); LDB_G(b, 0, 1, bfrB);
    MM32_G(); WAITVM(0); BARX();
    LDA_G(b, 1); LDB_G(b, 1, 0, bfrA); LDB_G(b, 1, 1, bfrB);
    MM32_G();
  }
#pragma unroll
  for (int mf = 0; mf < 4; ++mf)
#pragma unroll
    for (int nf = 0; nf < 4; ++nf) {
      int col = c0 + wn * 64 + nf * 16 + (l & 15);
      int rowb = m0 + wm * 64 + mf * 16 + (l >> 4) * 4;
#pragma unroll
      for (int r = 0; r < 4; ++r) {
        float g = acc[mf][nf][r], u = acc[mf][4 + nf][r];
        float s = g / (1.0f + __expf(-g));
        act[(size_t)(rowb + r) * SIDIM + col] = f2b(s * u);
      }
    }
#undef STA_G
#undef STB_G
#undef LDA_G
#undef LDB_G
#undef MM32_G
}

// ---- shared down
__global__ __launch_bounds__(512, 2) void dn_sh8(
    const u16* __restrict__ A, const u16* __restrict__ B, float* __restrict__ out) {
  extern __shared__ u16 sm[];
  u16* As  = sm;            // [2][2][8192]
  u16* Bsm = sm + 32768;    // [2][2][4096]
  const int bid = blockIdx.x;
  const int xcd = bid & 7, bi = bid >> 3;
  const int bx = xcd * 2 + (bi & 1), by = bi >> 1;
  const int m0 = by * 256, c0 = bx * 128;
  const int tid = threadIdx.x, l = tid & 63, wid = tid >> 6;
  const int wm = wid >> 1, wn = wid & 1;

  const int cpos = tid & 3, rr = tid >> 2;
  const int gc = (cpos ^ ((rr >> 1) & 3)) * 8;
  const u16* aS0 = A + (size_t)(m0 + rr) * SIDIM + gc;
  const u16* aS1 = A + (size_t)(m0 + 128 + rr) * SIDIM + gc;
  const u16* bS  = B + (size_t)(c0 + rr) * SIDIM + gc;
  const int ld0 = tid * 8, ld1 = (512 + tid) * 8;

#define STA_D(bb, kh, koff) do { \
    GLDS16(aS0 + (koff) + (kh) * 32, As + ((bb) * 2 + (kh)) * 8192 + ld0); \
    GLDS16(aS1 + (koff) + (kh) * 32, As + ((bb) * 2 + (kh)) * 8192 + ld1); } while (0)
#define STB_D(bb, kh, koff) \
    GLDS16(bS + (koff) + (kh) * 32, Bsm + ((bb) * 2 + (kh)) * 4096 + ld0)

  const int fch = ((l >> 4) ^ ((l >> 1) & 3)) * 8;
  int aoff[4], boff[4];
#pragma unroll
  for (int mf = 0; mf < 4; ++mf) aoff[mf] = (wm * 64 + mf * 16 + (l & 15)) * 32 + fch;
#pragma unroll
  for (int i = 0; i < 4; ++i) {
    int v = wn * 64 + (i >> 1) * 32 + (i & 1) * 16 + (l & 15);
    boff[i] = v * 32 + fch;
  }
#define LDA_D(bb, kh) do { const u16* s_ = As + ((bb) * 2 + (kh)) * 8192; \
    af[0] = *(const short8*)(s_ + aoff[0]); af[1] = *(const short8*)(s_ + aoff[1]); \
    af[2] = *(const short8*)(s_ + aoff[2]); af[3] = *(const short8*)(s_ + aoff[3]); } while (0)
#define LDB_D(bb, kh, h, d) do { const u16* s_ = Bsm + ((bb) * 2 + (kh)) * 4096; \
    d[0] = *(const short8*)(s_ + boff[(h) * 2 + 0]); \
    d[1] = *(const short8*)(s_ + boff[(h) * 2 + 1]); } while (0)
#define MM16_D() do { SETPRIO(1); \
    _Pragma("unroll") for (int mf = 0; mf < 4; ++mf) { \
      acc[mf][0] = __builtin_amdgcn_mfma_f32_16x16x32_bf16(af[mf], bfrA[0], acc[mf][0], 0, 0, 0); \
      acc[mf][1] = __builtin_amdgcn_mfma_f32_16x16x32_bf16(af[mf], bfrA[1], acc[mf][1], 0, 0, 0); \
      acc[mf][2] = __builtin_amdgcn_mfma_f32_16x16x32_bf16(af[mf], bfrB[0], acc[mf][2], 0, 0, 0); \
      acc[mf][3] = __builtin_amdgcn_mfma_f32_16x16x32_bf16(af[mf], bfrB[1], acc[mf][3], 0, 0, 0); \
    } SETPRIO(0); } while (0)

  f32x4 acc[4][4];
#pragma unroll
  for (int i = 0; i < 4; ++i)
#pragma unroll
    for (int j = 0; j < 4; ++j)
#pragma unroll
      for (int r = 0; r < 4; ++r) acc[i][j][r] = 0.0f;
  short8 af[4], bfrA[2], bfrB[2];

  STA_D(0, 0, 0); STB_D(0, 0, 0); STA_D(0, 1, 0); STB_D(0, 1, 0);
  WAITVM(3); BARX();
  const int NT = SIDIM / 64;
  for (int t = 0; t < NT - 1; ++t) {
    const int b = t & 1, nb = b ^ 1, kn = (t + 1) * 64;
    LDA_D(b, 0); LDB_D(b, 0, 0, bfrA); LDB_D(b, 0, 1, bfrB);
    STA_D(nb, 0, kn); STB_D(nb, 0, kn);
    MM16_D(); WAITVM(3); BARX();
    LDA_D(b, 1); LDB_D(b, 1, 0, bfrA); LDB_D(b, 1, 1, bfrB);
    STA_D(nb, 1, kn); STB_D(nb, 1, kn);
    MM16_D(); WAITVM(3); BARX();
  }
  { const int b = (NT - 1) & 1;
    LDA_D(b, 0); LDB_D(b, 0, 0, bfrA); LDB_D(b, 0, 1, bfrB);
    MM16_D(); WAITVM(0); BARX();
    LDA_D(b, 1); LDB_D(b, 1, 0, bfrA); LDB_D(b, 1, 1, bfrB);
    MM16_D();
  }
#pragma unroll
  for (int mf = 0; mf < 4; ++mf)
#pragma unroll
    for (int nf = 0; nf < 4; ++nf) {
      int col = c0 + wn * 64 + (nf >> 1) * 32 + (nf & 1) * 16 + (l & 15);
      int rowb = m0 + wm * 64 + mf * 16 + (l >> 4) * 4;
#pragma unroll
      for (int r = 0; r < 4; ++r)
        out[(size_t)(rowb + r) * HDIM + col] = acc[mf][nf][r];
    }
#undef STA_D
#undef STB_D
#undef LDA_D
#undef LDB_D
#undef MM16_D
}

// ================= routed GEMMs: round-6 proven scalar staging (best measured) =================
__global__ __launch_bounds__(256) void gu_rf(
    const u16* __restrict__ A, const float* __restrict__ Bg0, const float* __restrict__ Bu0,
    u16* __restrict__ act, const int* __restrict__ tile_exp) {
  __shared__ __align__(16) u16 As[128 * 64];
  __shared__ __align__(16) u16 Bgs[64 * 72];
  __shared__ __align__(16) u16 Bus[64 * 72];
  const int tid = threadIdx.x;
  const int l = tid & 63, w = tid >> 6;
  const int wm = w >> 1, wn = w & 1;
  const int m0 = blockIdx.y * 128, n0 = blockIdx.x * 64;
  int e = tile_exp[blockIdx.y];
  if (e < 0) return;
  size_t eo = (size_t)e * HDIM * IDIM;
  const float* Bg = Bg0 + eo;
  const float* Bu = Bu0 + eo;
  f32x4 accg[4][2], accu[4][2];
#pragma unroll
  for (int i = 0; i < 4; ++i)
#pragma unroll
    for (int j = 0; j < 2; ++j)
#pragma unroll
      for (int r = 0; r < 4; ++r) { accg[i][j][r] = 0.0f; accu[i][j][r] = 0.0f; }
  const u16* Ab = A + (size_t)m0 * HDIM;

  for (int k0 = 0; k0 < HDIM; k0 += 64) {
    __syncthreads();
#pragma unroll
    for (int j = 0; j < 4; ++j) {
      int c = j * 256 + tid, r = c >> 3, cc = c & 7;
      GLDS16(Ab + (size_t)r * HDIM + k0 + ((cc ^ (r & 7)) * 8), &As[c * 8]);
    }
    {
      const float* bp = Bg + (size_t)(k0 + w * 16) * IDIM + n0 + l;
      u16 h[16];
#pragma unroll
      for (int i = 0; i < 16; ++i) h[i] = f2b(bp[(size_t)i * IDIM]);
#pragma unroll
      for (int j = 0; j < 4; ++j) {
        uint2 v; v.x = (u32)h[4*j] | ((u32)h[4*j+1] << 16);
        v.y = (u32)h[4*j+2] | ((u32)h[4*j+3] << 16);
        *(uint2*)&Bgs[l * 72 + w * 16 + j * 4] = v;
      }
      bp = Bu + (size_t)(k0 + w * 16) * IDIM + n0 + l;
#pragma unroll
      for (int i = 0; i < 16; ++i) h[i] = f2b(bp[(size_t)i * IDIM]);
#pragma unroll
      for (int j = 0; j < 4; ++j) {
        uint2 v; v.x = (u32)h[4*j] | ((u32)h[4*j+1] << 16);
        v.y = (u32)h[4*j+2] | ((u32)h[4*j+3] << 16);
        *(uint2*)&Bus[l * 72 + w * 16 + j * 4] = v;
      }
    }
    __syncthreads();
#pragma unroll
    for (int kh = 0; kh < 2; ++kh) {
      const int q = kh * 4 + (l >> 4);
      short8 af[4];
#pragma unroll
      for (int mf = 0; mf < 4; ++mf) {
        int r = wm * 64 + mf * 16 + (l & 15);
        af[mf] = *(const short8*)&As[r * 64 + ((q ^ (r & 7)) * 8)];
      }
      short8 bgf[2], buf2[2];
#pragma unroll
      for (int nf = 0; nf < 2; ++nf) {
        int n = wn * 32 + nf * 16 + (l & 15);
        bgf[nf]  = *(const short8*)&Bgs[n * 72 + q * 8];
        buf2[nf] = *(const short8*)&Bus[n * 72 + q * 8];
      }
#pragma unroll
      for (int mf = 0; mf < 4; ++mf)
#pragma unroll
        for (int nf = 0; nf < 2; ++nf) {
          accg[mf][nf] = __builtin_amdgcn_mfma_f32_16x16x32_bf16(af[mf], bgf[nf],  accg[mf][nf], 0, 0, 0);
          accu[mf][nf] = __builtin_amdgcn_mfma_f32_16x16x32_bf16(af[mf], buf2[nf], accu[mf][nf], 0, 0, 0);
        }
    }
  }
#pragma unroll
  for (int mf = 0; mf < 4; ++mf)
#pragma unroll
    for (int nf = 0; nf < 2; ++nf) {
      int col = n0 + wn * 32 + nf * 16 + (l & 15);
#pragma unroll
      for (int r = 0; r < 4; ++r) {
        int row = m0 + wm * 64 + mf * 16 + (l >> 4) * 4 + r;
        float g = accg[mf][nf][r], u = accu[mf][nf][r];
        float s = g / (1.0f + __expf(-g));
        act[(size_t)row * IDIM + col] = f2b(s * u);
      }
    }
}

__global__ __launch_bounds__(256) void dn_rf(
    const u16* __restrict__ A, const float* __restrict__ B0, float* __restrict__ out,
    const int* __restrict__ tile_exp, const int* __restrict__ tok_row) {
  __shared__ __align__(16) u16 As[128 * 64];
  __shared__ __align__(16) u16 Bs[64 * 72];
  const int tid = threadIdx.x;
  const int l = tid & 63, w = tid >> 6;
  const int wm = w >> 1, wn = w & 1;
  const int m0 = blockIdx.y * 128, n0 = blockIdx.x * 64;
  int e = tile_exp[blockIdx.y];
  if (e < 0) return;
  const float* B = B0 + (size_t)e * IDIM * HDIM;
  f32x4 acc[4][2];
#pragma unroll
  for (int i = 0; i < 4; ++i)
#pragma unroll
    for (int j = 0; j < 2; ++j)
#pragma unroll
      for (int r = 0; r < 4; ++r) acc[i][j][r] = 0.0f;
  const u16* Ab = A + (size_t)m0 * IDIM;

  for (int k0 = 0; k0 < IDIM; k0 += 64) {
    __syncthreads();
#pragma unroll
    for (int j = 0; j < 4; ++j) {
      int c = j * 256 + tid, r = c >> 3, cc = c & 7;
      GLDS16(Ab + (size_t)r * IDIM + k0 + ((cc ^ (r & 7)) * 8), &As[c * 8]);
    }
    {
      const float* bp = B + (size_t)(k0 + w * 16) * HDIM + n0 + l;
      u16 h[16];
#pragma unroll
      for (int i = 0; i < 16; ++i) h[i] = f2b(bp[(size_t)i * HDIM]);
#pragma unroll
      for (int j = 0; j < 4; ++j) {
        uint2 v; v.x = (u32)h[4*j] | ((u32)h[4*j+1] << 16);
        v.y = (u32)h[4*j+2] | ((u32)h[4*j+3] << 16);
        *(uint2*)&Bs[l * 72 + w * 16 + j * 4] = v;
      }
    }
    __syncthreads();
#pragma unroll
    for (int kh = 0; kh < 2; ++kh) {
      const int q = kh * 4 + (l >> 4);
      short8 af[4];
#pragma unroll
      for (int mf = 0; mf < 4; ++mf) {
        int r = wm * 64 + mf * 16 + (l & 15);
        af[mf] = *(const short8*)&As[r * 64 + ((q ^ (r & 7)) * 8)];
      }
      short8 bf[2];
#pragma unroll
      for (int nf = 0; nf < 2; ++nf) {
        int n = wn * 32 + nf * 16 + (l & 15);
        bf[nf] = *(const short8*)&Bs[n * 72 + q * 8];
      }
#pragma unroll
      for (int mf = 0; mf < 4; ++mf)
#pragma unroll
        for (int nf = 0; nf < 2; ++nf)
          acc[mf][nf] = __builtin_amdgcn_mfma_f32_16x16x32_bf16(af[mf], bf[nf], acc[mf][nf], 0, 0, 0);
    }
  }
#pragma unroll
  for (int mf = 0; mf < 4; ++mf)
#pragma unroll
    for (int nf = 0; nf < 2; ++nf) {
      int col = n0 + wn * 32 + nf * 16 + (l & 15);
#pragma unroll
      for (int r = 0; r < 4; ++r) {
        int grow = m0 + wm * 64 + mf * 16 + (l >> 4) * 4 + r;
        int t = tok_row[grow];
        if (t >= 0) out[(size_t)t * HDIM + col] += acc[mf][nf][r];
      }
    }
}

extern "C" void kernel_launch(void* const* d_in, const int* in_sizes, int n_in,
                              void* d_out, int out_size, void* d_ws, size_t ws_size,
                              hipStream_t stream) {
  const float* x   = (const float*)d_in[0];
  const float* rw  = (const float*)d_in[1];
  const float* wg  = (const float*)d_in[2];
  const float* wu  = (const float*)d_in[3];
  const float* wd  = (const float*)d_in[4];
  const float* wsg = (const float*)d_in[5];
  const float* wsu = (const float*)d_in[6];
  const float* wsd = (const float*)d_in[7];
  float* out = (float*)d_out;
  char* ws = (char*)d_ws;

  float* wt     = (float*)(ws + O_WT);
  int* eidx     = (int*)(ws + O_EIDX);
  int* cnt      = (int*)(ws + O_CNT);
  int* pos      = (int*)(ws + O_POS);
  int* pad_off  = (int*)(ws + O_PADOFF);
  int* tile_exp = (int*)(ws + O_TILEEXP);
  int* tok_row  = (int*)(ws + O_TOKROW);
  u16* xbf      = (u16*)(ws + O_XBF);
  u16* xsc      = (u16*)(ws + O_XSC);
  u16* acts     = (u16*)(ws + O_ACTS);
  u16* actr     = (u16*)(ws + O_ACTR);
  u16* wsgT     = (u16*)(ws + O_WSGT);
  u16* wsuT     = (u16*)(ws + O_WSUT);
  u16* wsdT     = (u16*)(ws + O_WSDT);

  hipFuncSetAttribute((const void*)gu_sh8, hipFuncAttributeMaxDynamicSharedMemorySize, 131072);
  hipFuncSetAttribute((const void*)dn_sh8, hipFuncAttributeMaxDynamicSharedMemorySize, 98304);

  hipMemsetAsync(ws + O_CNT, 0, 128, stream);
  megart<<<7168, 256, 0, stream>>>(wsg, wsu, wsd, wsgT, wsuT, wsdT,
                                   x, rw, wt, eidx, cnt, xbf);
  scan_k<<<1, 256, 0, stream>>>(cnt, pad_off, tile_exp, pos, tok_row);
  assign_k<<<T_TOK / 256, 256, 0, stream>>>(eidx, pad_off, pos, tok_row);
  gather_k<<<RCAP, 256, 0, stream>>>(x, wt, tok_row, xsc);

  gu_sh8<<<512, 512, 131072, stream>>>(xbf, wsgT, wsuT, acts);
  gu_rf<<<dim3(IDIM / 64, NTIL), 256, 0, stream>>>(xsc, wg, wu, actr, tile_exp);
  dn_sh8<<<256, 512, 98304, stream>>>(acts, wsdT, out);
  dn_rf<<<dim3(HDIM / 64, NTIL), 256, 0, stream>>>(actr, wd, out, tile_exp, tok_row);
}

// Round 14
// 548.792 us; speedup vs baseline: 1.8523x; 1.0308x over previous
//
#include <hip/hip_runtime.h>
#include <hip/hip_bf16.h>

typedef unsigned short u16;
typedef unsigned int   u32;
typedef __attribute__((ext_vector_type(8))) short short8;   // 8 bf16 (MFMA A/B frag)
typedef __attribute__((ext_vector_type(4))) float f32x4;    // MFMA C/D frag

#define T_TOK 4096
#define HDIM  2048
#define NEXP  16
#define IDIM  1024
#define SIDIM 4096
#define RCAP  6144
#define NTIL  48

// ---- workspace layout (bytes) ----
#define O_WT      0u
#define O_EIDX    16384u
#define O_CNT     32768u
#define O_POS     32832u
#define O_PADOFF  32896u
#define O_TILEEXP 33024u
#define O_TOKROW  33280u
#define O_XBF     65536u                               // bf16[T][H]
#define O_XSC     (O_XBF  + 2u*T_TOK*HDIM)             // bf16[RCAP][H]
#define O_ACTS    (O_XSC  + 2u*RCAP*HDIM)              // bf16[T][SI]
#define O_ACTR    (O_ACTS + 2u*T_TOK*SIDIM)            // bf16[RCAP][I]
#define O_WSGT    (O_ACTR + 2u*RCAP*IDIM)              // bf16[SI][H]
#define O_WSUT    (O_WSGT + 2u*SIDIM*HDIM)
#define O_WSDT    (O_WSUT + 2u*SIDIM*HDIM)             // bf16[H][SI]

__device__ __forceinline__ u16 f2b(float f) {  // fp32 -> bf16, RNE
  u32 u = __float_as_uint(f);
  u = (u + 0x7FFFu + ((u >> 16) & 1u)) >> 16;
  return (u16)u;
}

#define GLDS16(g, l) __builtin_amdgcn_global_load_lds( \
    (const __attribute__((address_space(1))) void*)(g), \
    (__attribute__((address_space(3))) void*)(l), 16, 0, 0)
#define BARX() __builtin_amdgcn_s_barrier()
#define SETPRIO(x) __builtin_amdgcn_s_setprio(x)
#define WAITVM(n) asm volatile("s_waitcnt vmcnt(" #n ")" ::: "memory")

// ---------------- router v2: two 8-expert passes (8 fp64 accs each -> no spill) ----------------
__global__ __launch_bounds__(256) void router_k(
    const float* __restrict__ x, const float* __restrict__ rw,
    float* __restrict__ wt, int* __restrict__ eidx, int* __restrict__ cnt,
    u16* __restrict__ xbf) {
  int w = threadIdx.x >> 6, l = threadIdx.x & 63;
  int t = blockIdx.x * 4 + w;
  const float* xp = x + (size_t)t * HDIM;
  u16* xo = xbf + (size_t)t * HDIM;
  double best = 0.0; int be = -1;
#pragma unroll
  for (int eb = 0; eb < NEXP; eb += 8) {
    double acc[8];
#pragma unroll
    for (int e = 0; e < 8; ++e) acc[e] = 0.0;
    for (int hb = 0; hb < HDIM; hb += 256) {
      float4 xv = *(const float4*)(xp + hb + l * 4);
      if (eb == 0) {
        uint2 o;
        o.x = (u32)f2b(xv.x) | ((u32)f2b(xv.y) << 16);
        o.y = (u32)f2b(xv.z) | ((u32)f2b(xv.w) << 16);
        *(uint2*)(xo + hb + l * 4) = o;
      }
#pragma unroll
      for (int e = 0; e < 8; ++e) {
        float4 wv = *(const float4*)(rw + (size_t)(eb + e) * HDIM + hb + l * 4);
        acc[e] += (double)xv.x * wv.x + (double)xv.y * wv.y
                + (double)xv.z * wv.z + (double)xv.w * wv.w;
      }
    }
#pragma unroll
    for (int e = 0; e < 8; ++e) {
      double v = acc[e];
#pragma unroll
      for (int off = 32; off; off >>= 1) v += __shfl_xor(v, off, 64);
      if (l == 0) {
        if (be < 0 || v > best) { best = v; be = eb + e; }
      }
    }
  }
  if (l == 0) {
    wt[t] = 1.0f / (1.0f + __expf(-(float)best));
    eidx[t] = be;
    atomicAdd(&cnt[be], 1);
  }
}

// ---------------- shared-weight transpose-convert: fp32 [K][N] -> bf16 [N][K] ----------------
__device__ __forceinline__ void conv_tile(
    const float* __restrict__ src, u16* __restrict__ dst, int K, int N,
    int bx, int ky, u32 (*lt)[36], int tid) {
  const int n0 = bx * 64, k0 = ky * 64;
  const int l = tid & 63, w = tid >> 6;
  const float* sp = src + (size_t)(k0 + w * 16) * N + n0 + l;
  u32 p[8];
#pragma unroll
  for (int i = 0; i < 8; ++i) {
    float a = sp[(size_t)(2 * i) * N];
    float b = sp[(size_t)(2 * i + 1) * N];
    p[i] = (u32)f2b(a) | ((u32)f2b(b) << 16);
  }
  *(uint4*)&lt[l][w * 8 + 0] = make_uint4(p[0], p[1], p[2], p[3]);
  *(uint4*)&lt[l][w * 8 + 4] = make_uint4(p[4], p[5], p[6], p[7]);
  __syncthreads();
  const int c = tid & 7, n2 = tid >> 3;
#pragma unroll
  for (int rnd = 0; rnd < 2; ++rnd) {
    int n = n2 + rnd * 32;
    uint4 v = *(const uint4*)&lt[n][c * 4];
    *(uint4*)(dst + (size_t)(n0 + n) * K + k0 + c * 8) = v;
  }
}

__global__ __launch_bounds__(256) void megaconv(
    const float* __restrict__ wsg, const float* __restrict__ wsu,
    const float* __restrict__ wsd, u16* wsgT, u16* wsuT, u16* wsdT) {
  __shared__ u32 lt[64][36];
  int idx = blockIdx.x, tid = threadIdx.x;
  if (idx < 2048) {
    conv_tile(wsg, wsgT, 2048, 4096, idx & 63, idx >> 6, lt, tid);
  } else if (idx < 4096) { idx -= 2048;
    conv_tile(wsu, wsuT, 2048, 4096, idx & 63, idx >> 6, lt, tid);
  } else { idx -= 4096;
    conv_tile(wsd, wsdT, 4096, 2048, idx & 31, idx >> 5, lt, tid);
  }
}

__global__ void scan_k(const int* __restrict__ cnt, int* __restrict__ pad_off,
                       int* __restrict__ tile_exp, int* __restrict__ pos,
                       int* __restrict__ tok_row) {
  if (threadIdx.x == 0) {
    for (int i = 0; i < 64; ++i) tile_exp[i] = -1;
    int run = 0;
    for (int e = 0; e < NEXP; ++e) {
      pad_off[e] = run;
      int pc = ((cnt[e] + 127) >> 7) << 7;
      for (int tt = run >> 7; tt < (run + pc) >> 7; ++tt) tile_exp[tt] = e;
      run += pc;
      pos[e] = 0;
    }
    pad_off[NEXP] = run;
  }
  for (int i = threadIdx.x; i < RCAP; i += 256) tok_row[i] = -1;
}

__global__ void assign_k(const int* __restrict__ eidx, const int* __restrict__ pad_off,
                         int* __restrict__ pos, int* __restrict__ tok_row) {
  int t = blockIdx.x * 256 + threadIdx.x;
  if (t >= T_TOK) return;
  int e = eidx[t];
  int r = atomicAdd(&pos[e], 1);
  tok_row[pad_off[e] + r] = t;
}

// ---------------- gathered + router-weighted x -> xsc (bf16) ----------------
__global__ __launch_bounds__(256) void gather_k(
    const float* __restrict__ x, const float* __restrict__ wt,
    const int* __restrict__ tok_row, u16* __restrict__ xsc) {
  int g = blockIdx.x;
  int tid = threadIdx.x;
  u16* dst = xsc + (size_t)g * HDIM;
  int t = tok_row[g];
  if (t < 0) {
    uint2 z; z.x = 0u; z.y = 0u;
#pragma unroll
    for (int i = 0; i < 2; ++i) *(uint2*)(dst + i * 1024 + tid * 4) = z;
  } else {
    float s = wt[t];
    const float* src = x + (size_t)t * HDIM;
#pragma unroll
    for (int i = 0; i < 2; ++i) {
      int c = i * 1024 + tid * 4;
      float4 v = *(const float4*)(src + c);
      uint2 o;
      o.x = (u32)f2b(v.x * s) | ((u32)f2b(v.y * s) << 16);
      o.y = (u32)f2b(v.z * s) | ((u32)f2b(v.w * s) << 16);
      *(uint2*)(dst + c) = o;
    }
  }
}

// ================= merged-phase 256-row shared GEMMs (round-7, passing) =================

// ---- shared gate/up
__global__ __launch_bounds__(512, 2) void gu_sh8(
    const u16* __restrict__ A, const u16* __restrict__ Bg, const u16* __restrict__ Bu,
    u16* __restrict__ act) {
  extern __shared__ u16 sm[];
  u16* As  = sm;            // [2][2][8192]
  u16* Bsm = sm + 32768;    // [2][2][8192]
  const int bid = blockIdx.x;
  const int xcd = bid & 7, bi = bid >> 3;
  const int bx = xcd * 4 + (bi & 3), by = bi >> 2;
  const int m0 = by * 256, c0 = bx * 128;
  const int tid = threadIdx.x, l = tid & 63, wid = tid >> 6;
  const int wm = wid >> 1, wn = wid & 1;

  const int cpos = tid & 3, rr = tid >> 2;
  const int gc = (cpos ^ ((rr >> 1) & 3)) * 8;
  const u16* aS0 = A + (size_t)(m0 + rr) * HDIM + gc;
  const u16* aS1 = A + (size_t)(m0 + 128 + rr) * HDIM + gc;
  const int mat = (rr >> 6) & 1;
  const u16* bbase = mat ? Bu : Bg;
  const u16* bS0 = bbase + (size_t)(c0 + (rr & 63)) * HDIM + gc;
  const u16* bS1 = bbase + (size_t)(c0 + 64 + (rr & 63)) * HDIM + gc;
  const int ld0 = tid * 8, ld1 = (512 + tid) * 8;

#define STA_G(bb, kh, koff) do { \
    GLDS16(aS0 + (koff) + (kh) * 32, As + ((bb) * 2 + (kh)) * 8192 + ld0); \
    GLDS16(aS1 + (koff) + (kh) * 32, As + ((bb) * 2 + (kh)) * 8192 + ld1); } while (0)
#define STB_G(bb, kh, koff) do { \
    GLDS16(bS0 + (koff) + (kh) * 32, Bsm + ((bb) * 2 + (kh)) * 8192 + ld0); \
    GLDS16(bS1 + (koff) + (kh) * 32, Bsm + ((bb) * 2 + (kh)) * 8192 + ld1); } while (0)

  const int fch = ((l >> 4) ^ ((l >> 1) & 3)) * 8;
  int aoff[4], boff[8];
#pragma unroll
  for (int mf = 0; mf < 4; ++mf) aoff[mf] = (wm * 64 + mf * 16 + (l & 15)) * 32 + fch;
#pragma unroll
  for (int i = 0; i < 8; ++i) {
    int v = wn * 128 + (i >> 2) * 64 + (i & 3) * 16 + (l & 15);
    boff[i] = v * 32 + fch;
  }
#define LDA_G(bb, kh) do { const u16* s_ = As + ((bb) * 2 + (kh)) * 8192; \
    af[0] = *(const short8*)(s_ + aoff[0]); af[1] = *(const short8*)(s_ + aoff[1]); \
    af[2] = *(const short8*)(s_ + aoff[2]); af[3] = *(const short8*)(s_ + aoff[3]); } while (0)
#define LDB_G(bb, kh, h, d) do { const u16* s_ = Bsm + ((bb) * 2 + (kh)) * 8192; \
    d[0] = *(const short8*)(s_ + boff[(h) * 4 + 0]); d[1] = *(const short8*)(s_ + boff[(h) * 4 + 1]); \
    d[2] = *(const short8*)(s_ + boff[(h) * 4 + 2]); d[3] = *(const short8*)(s_ + boff[(h) * 4 + 3]); } while (0)
#define MM32_G() do { SETPRIO(1); \
    _Pragma("unroll") for (int mf = 0; mf < 4; ++mf) { \
      _Pragma("unroll") for (int nf = 0; nf < 4; ++nf) \
        acc[mf][nf] = __builtin_amdgcn_mfma_f32_16x16x32_bf16(af[mf], bfrA[nf], acc[mf][nf], 0, 0, 0); \
      _Pragma("unroll") for (int nf = 0; nf < 4; ++nf) \
        acc[mf][4 + nf] = __builtin_amdgcn_mfma_f32_16x16x32_bf16(af[mf], bfrB[nf], acc[mf][4 + nf], 0, 0, 0); \
    } SETPRIO(0); } while (0)

  f32x4 acc[4][8];
#pragma unroll
  for (int i = 0; i < 4; ++i)
#pragma unroll
    for (int j = 0; j < 8; ++j)
#pragma unroll
      for (int r = 0; r < 4; ++r) acc[i][j][r] = 0.0f;
  short8 af[4], bfrA[4], bfrB[4];

  STA_G(0, 0, 0); STB_G(0, 0, 0); STA_G(0, 1, 0); STB_G(0, 1, 0);
  WAITVM(4); BARX();
  const int NT = HDIM / 64;
  for (int t = 0; t < NT - 1; ++t) {
    const int b = t & 1, nb = b ^ 1, kn = (t + 1) * 64;
    LDA_G(b, 0); LDB_G(b, 0, 0, bfrA); LDB_G(b, 0, 1, bfrB);
    STA_G(nb, 0, kn); STB_G(nb, 0, kn);
    MM32_G(); WAITVM(4); BARX();
    LDA_G(b, 1); LDB_G(b, 1, 0, bfrA); LDB_G(b, 1, 1, bfrB);
    STA_G(nb, 1, kn); STB_G(nb, 1, kn);
    MM32_G(); WAITVM(4); BARX();
  }
  { const int b = (NT - 1) & 1;
    LDA_G(b, 0); LDB_G(b, 0, 0, bfrA); LDB_G(b, 0, 1, bfrB);
    MM32_G(); WAITVM(0); BARX();
    LDA_G(b, 1); LDB_G(b, 1, 0, bfrA); LDB_G(b, 1, 1, bfrB);
    MM32_G();
  }
#pragma unroll
  for (int mf = 0; mf < 4; ++mf)
#pragma unroll
    for (int nf = 0; nf < 4; ++nf) {
      int col = c0 + wn * 64 + nf * 16 + (l & 15);
      int rowb = m0 + wm * 64 + mf * 16 + (l >> 4) * 4;
#pragma unroll
      for (int r = 0; r < 4; ++r) {
        float g = acc[mf][nf][r], u = acc[mf][4 + nf][r];
        float s = g / (1.0f + __expf(-g));
        act[(size_t)(rowb + r) * SIDIM + col] = f2b(s * u);
      }
    }
#undef STA_G
#undef STB_G
#undef LDA_G
#undef LDB_G
#undef MM32_G
}

// ---- shared down
__global__ __launch_bounds__(512, 2) void dn_sh8(
    const u16* __restrict__ A, const u16* __restrict__ B, float* __restrict__ out) {
  extern __shared__ u16 sm[];
  u16* As  = sm;            // [2][2][8192]
  u16* Bsm = sm + 32768;    // [2][2][4096]
  const int bid = blockIdx.x;
  const int xcd = bid & 7, bi = bid >> 3;
  const int bx = xcd * 2 + (bi & 1), by = bi >> 1;
  const int m0 = by * 256, c0 = bx * 128;
  const int tid = threadIdx.x, l = tid & 63, wid = tid >> 6;
  const int wm = wid >> 1, wn = wid & 1;

  const int cpos = tid & 3, rr = tid >> 2;
  const int gc = (cpos ^ ((rr >> 1) & 3)) * 8;
  const u16* aS0 = A + (size_t)(m0 + rr) * SIDIM + gc;
  const u16* aS1 = A + (size_t)(m0 + 128 + rr) * SIDIM + gc;
  const u16* bS  = B + (size_t)(c0 + rr) * SIDIM + gc;
  const int ld0 = tid * 8, ld1 = (512 + tid) * 8;

#define STA_D(bb, kh, koff) do { \
    GLDS16(aS0 + (koff) + (kh) * 32, As + ((bb) * 2 + (kh)) * 8192 + ld0); \
    GLDS16(aS1 + (koff) + (kh) * 32, As + ((bb) * 2 + (kh)) * 8192 + ld1); } while (0)
#define STB_D(bb, kh, koff) \
    GLDS16(bS + (koff) + (kh) * 32, Bsm + ((bb) * 2 + (kh)) * 4096 + ld0)

  const int fch = ((l >> 4) ^ ((l >> 1) & 3)) * 8;
  int aoff[4], boff[4];
#pragma unroll
  for (int mf = 0; mf < 4; ++mf) aoff[mf] = (wm * 64 + mf * 16 + (l & 15)) * 32 + fch;
#pragma unroll
  for (int i = 0; i < 4; ++i) {
    int v = wn * 64 + (i >> 1) * 32 + (i & 1) * 16 + (l & 15);
    boff[i] = v * 32 + fch;
  }
#define LDA_D(bb, kh) do { const u16* s_ = As + ((bb) * 2 + (kh)) * 8192; \
    af[0] = *(const short8*)(s_ + aoff[0]); af[1] = *(const short8*)(s_ + aoff[1]); \
    af[2] = *(const short8*)(s_ + aoff[2]); af[3] = *(const short8*)(s_ + aoff[3]); } while (0)
#define LDB_D(bb, kh, h, d) do { const u16* s_ = Bsm + ((bb) * 2 + (kh)) * 4096; \
    d[0] = *(const short8*)(s_ + boff[(h) * 2 + 0]); \
    d[1] = *(const short8*)(s_ + boff[(h) * 2 + 1]); } while (0)
#define MM16_D() do { SETPRIO(1); \
    _Pragma("unroll") for (int mf = 0; mf < 4; ++mf) { \
      acc[mf][0] = __builtin_amdgcn_mfma_f32_16x16x32_bf16(af[mf], bfrA[0], acc[mf][0], 0, 0, 0); \
      acc[mf][1] = __builtin_amdgcn_mfma_f32_16x16x32_bf16(af[mf], bfrA[1], acc[mf][1], 0, 0, 0); \
      acc[mf][2] = __builtin_amdgcn_mfma_f32_16x16x32_bf16(af[mf], bfrB[0], acc[mf][2], 0, 0, 0); \
      acc[mf][3] = __builtin_amdgcn_mfma_f32_16x16x32_bf16(af[mf], bfrB[1], acc[mf][3], 0, 0, 0); \
    } SETPRIO(0); } while (0)

  f32x4 acc[4][4];
#pragma unroll
  for (int i = 0; i < 4; ++i)
#pragma unroll
    for (int j = 0; j < 4; ++j)
#pragma unroll
      for (int r = 0; r < 4; ++r) acc[i][j][r] = 0.0f;
  short8 af[4], bfrA[2], bfrB[2];

  STA_D(0, 0, 0); STB_D(0, 0, 0); STA_D(0, 1, 0); STB_D(0, 1, 0);
  WAITVM(3); BARX();
  const int NT = SIDIM / 64;
  for (int t = 0; t < NT - 1; ++t) {
    const int b = t & 1, nb = b ^ 1, kn = (t + 1) * 64;
    LDA_D(b, 0); LDB_D(b, 0, 0, bfrA); LDB_D(b, 0, 1, bfrB);
    STA_D(nb, 0, kn); STB_D(nb, 0, kn);
    MM16_D(); WAITVM(3); BARX();
    LDA_D(b, 1); LDB_D(b, 1, 0, bfrA); LDB_D(b, 1, 1, bfrB);
    STA_D(nb, 1, kn); STB_D(nb, 1, kn);
    MM16_D(); WAITVM(3); BARX();
  }
  { const int b = (NT - 1) & 1;
    LDA_D(b, 0); LDB_D(b, 0, 0, bfrA); LDB_D(b, 0, 1, bfrB);
    MM16_D(); WAITVM(0); BARX();
    LDA_D(b, 1); LDB_D(b, 1, 0, bfrA); LDB_D(b, 1, 1, bfrB);
    MM16_D();
  }
#pragma unroll
  for (int mf = 0; mf < 4; ++mf)
#pragma unroll
    for (int nf = 0; nf < 4; ++nf) {
      int col = c0 + wn * 64 + (nf >> 1) * 32 + (nf & 1) * 16 + (l & 15);
      int rowb = m0 + wm * 64 + mf * 16 + (l >> 4) * 4;
#pragma unroll
      for (int r = 0; r < 4; ++r)
        out[(size_t)(rowb + r) * HDIM + col] = acc[mf][nf][r];
    }
#undef STA_D
#undef STB_D
#undef LDA_D
#undef LDB_D
#undef MM16_D
}

// ================= routed GEMMs: round-6 proven scalar staging (best measured) =================
__global__ __launch_bounds__(256) void gu_rf(
    const u16* __restrict__ A, const float* __restrict__ Bg0, const float* __restrict__ Bu0,
    u16* __restrict__ act, const int* __restrict__ tile_exp) {
  __shared__ __align__(16) u16 As[128 * 64];
  __shared__ __align__(16) u16 Bgs[64 * 72];
  __shared__ __align__(16) u16 Bus[64 * 72];
  const int tid = threadIdx.x;
  const int l = tid & 63, w = tid >> 6;
  const int wm = w >> 1, wn = w & 1;
  const int m0 = blockIdx.y * 128, n0 = blockIdx.x * 64;
  int e = tile_exp[blockIdx.y];
  if (e < 0) return;
  size_t eo = (size_t)e * HDIM * IDIM;
  const float* Bg = Bg0 + eo;
  const float* Bu = Bu0 + eo;
  f32x4 accg[4][2], accu[4][2];
#pragma unroll
  for (int i = 0; i < 4; ++i)
#pragma unroll
    for (int j = 0; j < 2; ++j)
#pragma unroll
      for (int r = 0; r < 4; ++r) { accg[i][j][r] = 0.0f; accu[i][j][r] = 0.0f; }
  const u16* Ab = A + (size_t)m0 * HDIM;

  for (int k0 = 0; k0 < HDIM; k0 += 64) {
    __syncthreads();
#pragma unroll
    for (int j = 0; j < 4; ++j) {
      int c = j * 256 + tid, r = c >> 3, cc = c & 7;
      GLDS16(Ab + (size_t)r * HDIM + k0 + ((cc ^ (r & 7)) * 8), &As[c * 8]);
    }
    {
      const float* bp = Bg + (size_t)(k0 + w * 16) * IDIM + n0 + l;
      u16 h[16];
#pragma unroll
      for (int i = 0; i < 16; ++i) h[i] = f2b(bp[(size_t)i * IDIM]);
#pragma unroll
      for (int j = 0; j < 4; ++j) {
        uint2 v; v.x = (u32)h[4*j] | ((u32)h[4*j+1] << 16);
        v.y = (u32)h[4*j+2] | ((u32)h[4*j+3] << 16);
        *(uint2*)&Bgs[l * 72 + w * 16 + j * 4] = v;
      }
      bp = Bu + (size_t)(k0 + w * 16) * IDIM + n0 + l;
#pragma unroll
      for (int i = 0; i < 16; ++i) h[i] = f2b(bp[(size_t)i * IDIM]);
#pragma unroll
      for (int j = 0; j < 4; ++j) {
        uint2 v; v.x = (u32)h[4*j] | ((u32)h[4*j+1] << 16);
        v.y = (u32)h[4*j+2] | ((u32)h[4*j+3] << 16);
        *(uint2*)&Bus[l * 72 + w * 16 + j * 4] = v;
      }
    }
    __syncthreads();
#pragma unroll
    for (int kh = 0; kh < 2; ++kh) {
      const int q = kh * 4 + (l >> 4);
      short8 af[4];
#pragma unroll
      for (int mf = 0; mf < 4; ++mf) {
        int r = wm * 64 + mf * 16 + (l & 15);
        af[mf] = *(const short8*)&As[r * 64 + ((q ^ (r & 7)) * 8)];
      }
      short8 bgf[2], buf2[2];
#pragma unroll
      for (int nf = 0; nf < 2; ++nf) {
        int n = wn * 32 + nf * 16 + (l & 15);
        bgf[nf]  = *(const short8*)&Bgs[n * 72 + q * 8];
        buf2[nf] = *(const short8*)&Bus[n * 72 + q * 8];
      }
#pragma unroll
      for (int mf = 0; mf < 4; ++mf)
#pragma unroll
        for (int nf = 0; nf < 2; ++nf) {
          accg[mf][nf] = __builtin_amdgcn_mfma_f32_16x16x32_bf16(af[mf], bgf[nf],  accg[mf][nf], 0, 0, 0);
          accu[mf][nf] = __builtin_amdgcn_mfma_f32_16x16x32_bf16(af[mf], buf2[nf], accu[mf][nf], 0, 0, 0);
        }
    }
  }
#pragma unroll
  for (int mf = 0; mf < 4; ++mf)
#pragma unroll
    for (int nf = 0; nf < 2; ++nf) {
      int col = n0 + wn * 32 + nf * 16 + (l & 15);
#pragma unroll
      for (int r = 0; r < 4; ++r) {
        int row = m0 + wm * 64 + mf * 16 + (l >> 4) * 4 + r;
        float g = accg[mf][nf][r], u = accu[mf][nf][r];
        float s = g / (1.0f + __expf(-g));
        act[(size_t)row * IDIM + col] = f2b(s * u);
      }
    }
}

__global__ __launch_bounds__(256) void dn_rf(
    const u16* __restrict__ A, const float* __restrict__ B0, float* __restrict__ out,
    const int* __restrict__ tile_exp, const int* __restrict__ tok_row) {
  __shared__ __align__(16) u16 As[128 * 64];
  __shared__ __align__(16) u16 Bs[64 * 72];
  const int tid = threadIdx.x;
  const int l = tid & 63, w = tid >> 6;
  const int wm = w >> 1, wn = w & 1;
  const int m0 = blockIdx.y * 128, n0 = blockIdx.x * 64;
  int e = tile_exp[blockIdx.y];
  if (e < 0) return;
  const float* B = B0 + (size_t)e * IDIM * HDIM;
  f32x4 acc[4][2];
#pragma unroll
  for (int i = 0; i < 4; ++i)
#pragma unroll
    for (int j = 0; j < 2; ++j)
#pragma unroll
      for (int r = 0; r < 4; ++r) acc[i][j][r] = 0.0f;
  const u16* Ab = A + (size_t)m0 * IDIM;

  for (int k0 = 0; k0 < IDIM; k0 += 64) {
    __syncthreads();
#pragma unroll
    for (int j = 0; j < 4; ++j) {
      int c = j * 256 + tid, r = c >> 3, cc = c & 7;
      GLDS16(Ab + (size_t)r * IDIM + k0 + ((cc ^ (r & 7)) * 8), &As[c * 8]);
    }
    {
      const float* bp = B + (size_t)(k0 + w * 16) * HDIM + n0 + l;
      u16 h[16];
#pragma unroll
      for (int i = 0; i < 16; ++i) h[i] = f2b(bp[(size_t)i * HDIM]);
#pragma unroll
      for (int j = 0; j < 4; ++j) {
        uint2 v; v.x = (u32)h[4*j] | ((u32)h[4*j+1] << 16);
        v.y = (u32)h[4*j+2] | ((u32)h[4*j+3] << 16);
        *(uint2*)&Bs[l * 72 + w * 16 + j * 4] = v;
      }
    }
    __syncthreads();
#pragma unroll
    for (int kh = 0; kh < 2; ++kh) {
      const int q = kh * 4 + (l >> 4);
      short8 af[4];
#pragma unroll
      for (int mf = 0; mf < 4; ++mf) {
        int r = wm * 64 + mf * 16 + (l & 15);
        af[mf] = *(const short8*)&As[r * 64 + ((q ^ (r & 7)) * 8)];
      }
      short8 bf[2];
#pragma unroll
      for (int nf = 0; nf < 2; ++nf) {
        int n = wn * 32 + nf * 16 + (l & 15);
        bf[nf] = *(const short8*)&Bs[n * 72 + q * 8];
      }
#pragma unroll
      for (int mf = 0; mf < 4; ++mf)
#pragma unroll
        for (int nf = 0; nf < 2; ++nf)
          acc[mf][nf] = __builtin_amdgcn_mfma_f32_16x16x32_bf16(af[mf], bf[nf], acc[mf][nf], 0, 0, 0);
    }
  }
#pragma unroll
  for (int mf = 0; mf < 4; ++mf)
#pragma unroll
    for (int nf = 0; nf < 2; ++nf) {
      int col = n0 + wn * 32 + nf * 16 + (l & 15);
#pragma unroll
      for (int r = 0; r < 4; ++r) {
        int grow = m0 + wm * 64 + mf * 16 + (l >> 4) * 4 + r;
        int t = tok_row[grow];
        if (t >= 0) out[(size_t)t * HDIM + col] += acc[mf][nf][r];
      }
    }
}

extern "C" void kernel_launch(void* const* d_in, const int* in_sizes, int n_in,
                              void* d_out, int out_size, void* d_ws, size_t ws_size,
                              hipStream_t stream) {
  const float* x   = (const float*)d_in[0];
  const float* rw  = (const float*)d_in[1];
  const float* wg  = (const float*)d_in[2];
  const float* wu  = (const float*)d_in[3];
  const float* wd  = (const float*)d_in[4];
  const float* wsg = (const float*)d_in[5];
  const float* wsu = (const float*)d_in[6];
  const float* wsd = (const float*)d_in[7];
  float* out = (float*)d_out;
  char* ws = (char*)d_ws;

  float* wt     = (float*)(ws + O_WT);
  int* eidx     = (int*)(ws + O_EIDX);
  int* cnt      = (int*)(ws + O_CNT);
  int* pos      = (int*)(ws + O_POS);
  int* pad_off  = (int*)(ws + O_PADOFF);
  int* tile_exp = (int*)(ws + O_TILEEXP);
  int* tok_row  = (int*)(ws + O_TOKROW);
  u16* xbf      = (u16*)(ws + O_XBF);
  u16* xsc      = (u16*)(ws + O_XSC);
  u16* acts     = (u16*)(ws + O_ACTS);
  u16* actr     = (u16*)(ws + O_ACTR);
  u16* wsgT     = (u16*)(ws + O_WSGT);
  u16* wsuT     = (u16*)(ws + O_WSUT);
  u16* wsdT     = (u16*)(ws + O_WSDT);

  hipFuncSetAttribute((const void*)gu_sh8, hipFuncAttributeMaxDynamicSharedMemorySize, 131072);
  hipFuncSetAttribute((const void*)dn_sh8, hipFuncAttributeMaxDynamicSharedMemorySize, 98304);

  hipMemsetAsync(ws + O_CNT, 0, 128, stream);
  router_k<<<T_TOK / 4, 256, 0, stream>>>(x, rw, wt, eidx, cnt, xbf);
  megaconv<<<6144, 256, 0, stream>>>(wsg, wsu, wsd, wsgT, wsuT, wsdT);
  scan_k<<<1, 256, 0, stream>>>(cnt, pad_off, tile_exp, pos, tok_row);
  assign_k<<<T_TOK / 256, 256, 0, stream>>>(eidx, pad_off, pos, tok_row);
  gather_k<<<RCAP, 256, 0, stream>>>(x, wt, tok_row, xsc);

  gu_sh8<<<512, 512, 131072, stream>>>(xbf, wsgT, wsuT, acts);
  gu_rf<<<dim3(IDIM / 64, NTIL), 256, 0, stream>>>(xsc, wg, wu, actr, tile_exp);
  dn_sh8<<<256, 512, 98304, stream>>>(acts, wsdT, out);
  dn_rf<<<dim3(HDIM / 64, NTIL), 256, 0, stream>>>(actr, wd, out, tile_exp, tok_row);
}